// Round 1
// baseline (274.184 us; speedup 1.0000x reference)
//
#include <hip/hip_runtime.h>
#include <math.h>

// MidpointMLR: B=1048576, F_IN=F_OUT=64, c=1 (rc=1), EPS=1e-15
// out = proj( sinh( 2*z_norm * asinh( (2*(x@z_unit)*cosh(2b) - (1+||x||^2)*sinh(2b)) / max(1-||x||^2, eps) ) ) )

#define MLR_B 1048576
#define MLR_F 64

// ---------------- prep: z -> z_unit (k-major), per-col constants ----------------
// ws layout (floats): [0..4095] z_unit[k*64+o], [4096..4159] 2*cosh(2b),
//                     [4160..4223] sinh(2b),    [4224..4287] 2*z_norm
__global__ void mlr_prep_kernel(const float* __restrict__ z,
                                const float* __restrict__ bias,
                                float* __restrict__ ws) {
    int o = threadIdx.x;  // 64 threads, one per output column
    float n2 = 0.f;
    for (int k = 0; k < 64; ++k) {
        float v = z[k * 64 + o];
        n2 = fmaf(v, v, n2);
    }
    float zn  = fmaxf(sqrtf(n2), 1e-15f);
    float inv = 1.f / zn;
    for (int k = 0; k < 64; ++k) ws[k * 64 + o] = z[k * 64 + o] * inv;
    float d = 2.f * bias[o];
    ws[4096 + o] = 2.f * coshf(d);   // folds the leading 2 of num
    ws[4160 + o] = sinhf(d);
    ws[4224 + o] = 2.f * zn;
}

// y = sinh( g * asinh(t) ),  g = 2*z_norm, computed via exp/log (stable via |t|)
__device__ __forceinline__ float poin_y(float dot, float ch2, float sh, float g,
                                        float opc, float rden) {
    float t = fmaf(dot, ch2, -(opc * sh)) * rden;  // num/den
    float a = fabsf(t);
    float u = a + sqrtf(fmaf(a, a, 1.f));          // e^{asinh|t|}, >= 1
    float l = __logf(u);
    float w = __expf(g * l);                        // u^g
    float y = 0.5f * (w - __builtin_amdgcn_rcpf(w));
    return copysignf(y, t);
}

// ---------------- main: one thread per row ----------------
__global__ __launch_bounds__(256) void mlr_main_kernel(const float* __restrict__ x,
                                                       const float* __restrict__ ws,
                                                       float* __restrict__ out) {
    __shared__ float4 zL[1024];   // z_unit, k-major: zL[k*16 + o4]
    __shared__ float4 chL[16];
    __shared__ float4 shL[16];
    __shared__ float4 gL[16];

    const float4* wsv = (const float4*)ws;
    for (int i = threadIdx.x; i < 1024; i += 256) zL[i] = wsv[i];
    if (threadIdx.x < 48) {
        float4 v = wsv[1024 + threadIdx.x];
        if (threadIdx.x < 16)      chL[threadIdx.x]      = v;
        else if (threadIdx.x < 32) shL[threadIdx.x - 16] = v;
        else                       gL[threadIdx.x - 32]  = v;
    }
    __syncthreads();

    size_t row = (size_t)blockIdx.x * 256 + threadIdx.x;
    const float4* xr = (const float4*)(x + row * 64);

    float4 acc[16];
#pragma unroll
    for (int i = 0; i < 16; ++i) acc[i] = make_float4(0.f, 0.f, 0.f, 0.f);
    float cx2 = 0.f;

    // 4 k-chunks of 16; dynamic loop keeps code inside I$, all reg indexing static
    for (int c = 0; c < 4; ++c) {
        float4 xv0 = xr[4 * c + 0];
        float4 xv1 = xr[4 * c + 1];
        float4 xv2 = xr[4 * c + 2];
        float4 xv3 = xr[4 * c + 3];
        float xk[16];
        xk[0] = xv0.x; xk[1] = xv0.y; xk[2]  = xv0.z; xk[3]  = xv0.w;
        xk[4] = xv1.x; xk[5] = xv1.y; xk[6]  = xv1.z; xk[7]  = xv1.w;
        xk[8] = xv2.x; xk[9] = xv2.y; xk[10] = xv2.z; xk[11] = xv2.w;
        xk[12] = xv3.x; xk[13] = xv3.y; xk[14] = xv3.z; xk[15] = xv3.w;
#pragma unroll
        for (int j = 0; j < 16; ++j) cx2 = fmaf(xk[j], xk[j], cx2);

        const float4* zp = zL + c * 256;  // 16 k-rows x 16 float4-cols
#pragma unroll
        for (int o4 = 0; o4 < 16; ++o4) {
            float4 a = acc[o4];
#pragma unroll
            for (int j = 0; j < 16; ++j) {
                float4 zv = zp[j * 16 + o4];   // wave-uniform broadcast read
                float  s  = xk[j];
                a.x = fmaf(s, zv.x, a.x);
                a.y = fmaf(s, zv.y, a.y);
                a.z = fmaf(s, zv.z, a.z);
                a.w = fmaf(s, zv.w, a.w);
            }
            acc[o4] = a;
        }
    }

    // epilogue: logits -> y (in place in acc), row-sum of y^2, projection
    float opc  = 1.f + cx2;
    float rden = __builtin_amdgcn_rcpf(fmaxf(1.f - cx2, 1e-15f));
    float S = 0.f;
#pragma unroll
    for (int o4 = 0; o4 < 16; ++o4) {
        float4 d  = acc[o4];
        float4 ch = chL[o4];
        float4 sh = shL[o4];
        float4 g  = gL[o4];
        float4 y;
        y.x = poin_y(d.x, ch.x, sh.x, g.x, opc, rden);
        y.y = poin_y(d.y, ch.y, sh.y, g.y, opc, rden);
        y.z = poin_y(d.z, ch.z, sh.z, g.z, opc, rden);
        y.w = poin_y(d.w, ch.w, sh.w, g.w, opc, rden);
        S = fmaf(y.x, y.x, S);
        S = fmaf(y.y, y.y, S);
        S = fmaf(y.z, y.z, S);
        S = fmaf(y.w, y.w, S);
        acc[o4] = y;
    }
    float scale = __builtin_amdgcn_rcpf(1.f + sqrtf(1.f + S));

    float4* op = (float4*)(out + row * 64);
#pragma unroll
    for (int o4 = 0; o4 < 16; ++o4) {
        float4 y = acc[o4];
        y.x *= scale; y.y *= scale; y.z *= scale; y.w *= scale;
        op[o4] = y;
    }
}

extern "C" void kernel_launch(void* const* d_in, const int* in_sizes, int n_in,
                              void* d_out, int out_size, void* d_ws, size_t ws_size,
                              hipStream_t stream) {
    const float* x    = (const float*)d_in[0];
    const float* z    = (const float*)d_in[1];
    const float* bias = (const float*)d_in[2];
    float* out = (float*)d_out;
    float* ws  = (float*)d_ws;

    mlr_prep_kernel<<<dim3(1), dim3(64), 0, stream>>>(z, bias, ws);
    mlr_main_kernel<<<dim3(MLR_B / 256), dim3(256), 0, stream>>>(x, ws, out);
}

// Round 2
// 260.514 us; speedup vs baseline: 1.0525x; 1.0525x over previous
//
#include <hip/hip_runtime.h>
#include <math.h>

// MidpointMLR: B=1048576, F_IN=F_OUT=64, c=1 (rc=1), EPS=1e-15
// out = proj( sinh( 2*z_norm * asinh( (2*(x@z_unit)*cosh(2b) - (1+||x||^2)*sinh(2b)) / max(1-||x||^2, eps) ) ) )

#define MLR_B 1048576
#define MLR_F 64

// ---------------- prep: z -> z_unit (k-major), per-col constants ----------------
// ws layout (floats): [0..4095] z_unit[k*64+o], [4096..4159] 2*cosh(2b),
//                     [4160..4223] sinh(2b),    [4224..4287] 2*z_norm
__global__ void mlr_prep_kernel(const float* __restrict__ z,
                                const float* __restrict__ bias,
                                float* __restrict__ ws) {
    int o = threadIdx.x;  // 64 threads, one per output column
    float n2 = 0.f;
    for (int k = 0; k < 64; ++k) {
        float v = z[k * 64 + o];
        n2 = fmaf(v, v, n2);
    }
    float zn  = fmaxf(sqrtf(n2), 1e-15f);
    float inv = 1.f / zn;
    for (int k = 0; k < 64; ++k) ws[k * 64 + o] = z[k * 64 + o] * inv;
    float d = 2.f * bias[o];
    ws[4096 + o] = 2.f * coshf(d);   // folds the leading 2 of num
    ws[4160 + o] = sinhf(d);
    ws[4224 + o] = 2.f * zn;
}

// y = sinh( g * asinh(t) ),  g = 2*z_norm, computed via exp/log (stable via |t|)
__device__ __forceinline__ float poin_y(float dot, float ch2, float sh, float g,
                                        float opc, float rden) {
    float t = fmaf(dot, ch2, -(opc * sh)) * rden;  // num/den
    float a = fabsf(t);
    float u = a + sqrtf(fmaf(a, a, 1.f));          // e^{asinh|t|}, >= 1
    float l = __logf(u);
    float w = __expf(g * l);                        // u^g
    float y = 0.5f * (w - __builtin_amdgcn_rcpf(w));
    return copysignf(y, t);
}

// ---------------- main: one thread per row; z via wave-uniform scalar loads ----------------
__global__ __launch_bounds__(256) void mlr_main_kernel(const float* __restrict__ x,
                                                       const float* __restrict__ ws,
                                                       float* __restrict__ out) {
    size_t row = (size_t)blockIdx.x * 256 + threadIdx.x;
    const float4* xr = (const float4*)(x + row * 64);

    float4 acc[16];
#pragma unroll
    for (int i = 0; i < 16; ++i) acc[i] = make_float4(0.f, 0.f, 0.f, 0.f);
    float cx2 = 0.f;

    // 4 k-chunks of 16; all z accesses are thread-uniform -> s_load through K$
    for (int c = 0; c < 4; ++c) {
        float4 xv0 = xr[4 * c + 0];
        float4 xv1 = xr[4 * c + 1];
        float4 xv2 = xr[4 * c + 2];
        float4 xv3 = xr[4 * c + 3];
        float xk[16];
        xk[0] = xv0.x; xk[1] = xv0.y; xk[2]  = xv0.z; xk[3]  = xv0.w;
        xk[4] = xv1.x; xk[5] = xv1.y; xk[6]  = xv1.z; xk[7]  = xv1.w;
        xk[8] = xv2.x; xk[9] = xv2.y; xk[10] = xv2.z; xk[11] = xv2.w;
        xk[12] = xv3.x; xk[13] = xv3.y; xk[14] = xv3.z; xk[15] = xv3.w;
#pragma unroll
        for (int j = 0; j < 16; ++j) cx2 = fmaf(xk[j], xk[j], cx2);

        const float* zc = ws + c * 1024;  // 16 k-rows x 64 cols, k-major
#pragma unroll
        for (int j = 0; j < 16; ++j) {
            float s = xk[j];
            const float* zr = zc + j * 64;
#pragma unroll
            for (int o4 = 0; o4 < 16; ++o4) {
                // zr[*] is wave-uniform -> SGPR; FMA = v_fmac(v_acc, s_z, v_xk)
                acc[o4].x = fmaf(s, zr[o4 * 4 + 0], acc[o4].x);
                acc[o4].y = fmaf(s, zr[o4 * 4 + 1], acc[o4].y);
                acc[o4].z = fmaf(s, zr[o4 * 4 + 2], acc[o4].z);
                acc[o4].w = fmaf(s, zr[o4 * 4 + 3], acc[o4].w);
            }
        }
    }

    // epilogue: logits -> y (in place in acc), row-sum of y^2, projection
    const float* chp = ws + 4096;
    const float* shp = ws + 4160;
    const float* gp  = ws + 4224;
    float opc  = 1.f + cx2;
    float rden = __builtin_amdgcn_rcpf(fmaxf(1.f - cx2, 1e-15f));
    float S = 0.f;
#pragma unroll
    for (int o4 = 0; o4 < 16; ++o4) {
        float4 d = acc[o4];
        float4 y;
        y.x = poin_y(d.x, chp[o4 * 4 + 0], shp[o4 * 4 + 0], gp[o4 * 4 + 0], opc, rden);
        y.y = poin_y(d.y, chp[o4 * 4 + 1], shp[o4 * 4 + 1], gp[o4 * 4 + 1], opc, rden);
        y.z = poin_y(d.z, chp[o4 * 4 + 2], shp[o4 * 4 + 2], gp[o4 * 4 + 2], opc, rden);
        y.w = poin_y(d.w, chp[o4 * 4 + 3], shp[o4 * 4 + 3], gp[o4 * 4 + 3], opc, rden);
        S = fmaf(y.x, y.x, S);
        S = fmaf(y.y, y.y, S);
        S = fmaf(y.z, y.z, S);
        S = fmaf(y.w, y.w, S);
        acc[o4] = y;
    }
    float scale = __builtin_amdgcn_rcpf(1.f + sqrtf(1.f + S));

    float4* op = (float4*)(out + row * 64);
#pragma unroll
    for (int o4 = 0; o4 < 16; ++o4) {
        float4 y = acc[o4];
        y.x *= scale; y.y *= scale; y.z *= scale; y.w *= scale;
        op[o4] = y;
    }
}

extern "C" void kernel_launch(void* const* d_in, const int* in_sizes, int n_in,
                              void* d_out, int out_size, void* d_ws, size_t ws_size,
                              hipStream_t stream) {
    const float* x    = (const float*)d_in[0];
    const float* z    = (const float*)d_in[1];
    const float* bias = (const float*)d_in[2];
    float* out = (float*)d_out;
    float* ws  = (float*)d_ws;

    mlr_prep_kernel<<<dim3(1), dim3(64), 0, stream>>>(z, bias, ws);
    mlr_main_kernel<<<dim3(MLR_B / 256), dim3(256), 0, stream>>>(x, ws, out);
}

// Round 3
// 124.829 us; speedup vs baseline: 2.1965x; 2.0870x over previous
//
#include <hip/hip_runtime.h>
#include <math.h>

// MidpointMLR: B=1048576, F=64, c=1.
// out = proj( sinh( 2*z_norm * asinh( (2*(x@zu)*cosh(2b) - (1+cx2)*sinh(2b)) / max(1-cx2,eps) ) ) )

#define MLR_B 1048576

typedef __bf16 bf16x8 __attribute__((ext_vector_type(8)));
typedef float  f32x4  __attribute__((ext_vector_type(4)));

// ---------------- prep: z -> z_unit bf16 fragments + per-col constants ----------------
// ws layout: bytes [0,8192): zfrag[8][512] __bf16, frag i = s*4+t holds
//   zf[i*512 + (hi*16+col)*8 + e] = bf16( z_unit[k = 32s+8hi+e][16t+col] )
// bytes [8192,...): f32 cst[0..63]=2cosh(2b), [64..127]=sinh(2b), [128..191]=2*z_norm
__global__ void mlr_prep_kernel(const float* __restrict__ z,
                                const float* __restrict__ bias,
                                void* __restrict__ wsv) {
    __bf16* zf  = (__bf16*)wsv;
    float*  cst = (float*)((char*)wsv + 8192);
    int o = threadIdx.x;            // one thread per output column, 64 threads
    float n2 = 0.f;
    for (int k = 0; k < 64; ++k) { float v = z[k * 64 + o]; n2 = fmaf(v, v, n2); }
    float zn  = fmaxf(sqrtf(n2), 1e-15f);
    float inv = 1.f / zn;
    int t = o >> 4, c = o & 15;
    for (int k = 0; k < 64; ++k) {
        float zu = z[k * 64 + o] * inv;
        int s = k >> 5, r = k & 31, hi = r >> 3, e = r & 7;
        zf[(s * 4 + t) * 512 + (hi * 16 + c) * 8 + e] = (__bf16)zu;   // RNE fptrunc
    }
    float d = 2.f * bias[o];
    cst[o]       = 2.f * coshf(d);
    cst[64 + o]  = sinhf(d);
    cst[128 + o] = 2.f * zn;
}

// y = sinh( g * asinh(t) ) via exp/log, stable in |t|
__device__ __forceinline__ float poin_y(float dot, float ch2, float sh, float g,
                                        float opc, float rden) {
    float t = fmaf(dot, ch2, -(opc * sh)) * rden;
    float a = fabsf(t);
    float u = a + sqrtf(fmaf(a, a, 1.f));
    float w = __expf(g * __logf(u));
    float y = 0.5f * (w - __builtin_amdgcn_rcpf(w));
    return copysignf(y, t);
}

// ---------------- main: MFMA 16x16x32 bf16, 16 rows per wave-step ----------------
__global__ __launch_bounds__(256) void mlr_main_kernel(const float* __restrict__ x,
                                                       const void* __restrict__ wsv,
                                                       float* __restrict__ out) {
    const __bf16* zf  = (const __bf16*)wsv;
    const float*  cst = (const float*)((const char*)wsv + 8192);
    const int tid  = threadIdx.x;
    const int lane = tid & 63;
    const int lo   = lane & 15;     // A-row / B-col / C-col index
    const int hi   = lane >> 4;     // k-group / C-row-group
    const int wv   = blockIdx.x * 4 + (tid >> 6);

    // one-time: B fragments (z_unit), coalesced dwordx4 per (s,t)
    bf16x8 bfr[8];
#pragma unroll
    for (int i = 0; i < 8; ++i)
        bfr[i] = *(const bf16x8*)((const char*)zf + i * 1024 + lane * 16);
    // one-time: per-col epilogue constants for cols 16t+lo
    float ch[4], sh[4], g2[4];
#pragma unroll
    for (int t = 0; t < 4; ++t) {
        ch[t] = cst[16 * t + lo];
        sh[t] = cst[64 + 16 * t + lo];
        g2[t] = cst[128 + 16 * t + lo];
    }

    const size_t rowbase0 = (size_t)wv * 128;          // 8 steps x 16 rows
    const char* xb = (const char*)x + (rowbase0 + (size_t)lo) * 256 + hi * 32;

    // preload step 0 (per lane: row lo, k-bytes [s*128+hi*32, +32) )
    f32x4 c0 = *(const f32x4*)(xb + 0);
    f32x4 c1 = *(const f32x4*)(xb + 16);
    f32x4 c2 = *(const f32x4*)(xb + 128);
    f32x4 c3 = *(const f32x4*)(xb + 144);

    for (int it = 0; it < 8; ++it) {
        f32x4 n0 = c0, n1 = c1, n2 = c2, n3 = c3;
        if (it < 7) {                                   // uniform branch: prefetch next
            const char* xn = xb + (size_t)(it + 1) * 4096;
            n0 = *(const f32x4*)(xn + 0);
            n1 = *(const f32x4*)(xn + 16);
            n2 = *(const f32x4*)(xn + 128);
            n3 = *(const f32x4*)(xn + 144);
        }

        // cx2 partial from this lane's 16 f32 (rows lo, its k-slice)
        float p = 0.f;
#pragma unroll
        for (int j = 0; j < 4; ++j) {
            p = fmaf(c0[j], c0[j], p); p = fmaf(c1[j], c1[j], p);
            p = fmaf(c2[j], c2[j], p); p = fmaf(c3[j], c3[j], p);
        }
        p += __shfl_xor(p, 16);
        p += __shfl_xor(p, 32);                        // full cx2 for row lo

        // A fragments: k = 32s + 8hi + e  (same perm as B)
        bf16x8 a0, a1;
#pragma unroll
        for (int j = 0; j < 4; ++j) {
            a0[j]     = (__bf16)c0[j];
            a0[4 + j] = (__bf16)c1[j];
            a1[j]     = (__bf16)c2[j];
            a1[4 + j] = (__bf16)c3[j];
        }

        f32x4 acc[4];
#pragma unroll
        for (int t = 0; t < 4; ++t) {
            acc[t] = (f32x4){0.f, 0.f, 0.f, 0.f};
            acc[t] = __builtin_amdgcn_mfma_f32_16x16x32_bf16(a0, bfr[t],     acc[t], 0, 0, 0);
            acc[t] = __builtin_amdgcn_mfma_f32_16x16x32_bf16(a1, bfr[4 + t], acc[t], 0, 0, 0);
        }

        // epilogue: C/D map col=lo, row=4*hi+reg
        float y[4][4]; float S[4];
#pragma unroll
        for (int r = 0; r < 4; ++r) {
            float cxr  = __shfl(p, hi * 4 + r);        // cx2 of row 4*hi+r
            float opc  = 1.f + cxr;
            float rden = __builtin_amdgcn_rcpf(fmaxf(1.f - cxr, 1e-15f));
            float s0 = 0.f;
#pragma unroll
            for (int t = 0; t < 4; ++t) {
                float v = poin_y(acc[t][r], ch[t], sh[t], g2[t], opc, rden);
                y[r][t] = v;
                s0 = fmaf(v, v, s0);
            }
            S[r] = s0;
        }
#pragma unroll
        for (int r = 0; r < 4; ++r) {
            float s0 = S[r];
            s0 += __shfl_xor(s0, 1);
            s0 += __shfl_xor(s0, 2);
            s0 += __shfl_xor(s0, 4);
            s0 += __shfl_xor(s0, 8);                   // sum over all 64 cols of row
            float scale = __builtin_amdgcn_rcpf(1.f + sqrtf(1.f + s0));
#pragma unroll
            for (int t = 0; t < 4; ++t) y[r][t] *= scale;
        }

        // stores: per (r,t) lanes 0..15 write 64B contiguous -> full-line writes
        char* ob = (char*)out + (rowbase0 + it * 16 + hi * 4) * 256 + lo * 4;
#pragma unroll
        for (int r = 0; r < 4; ++r)
#pragma unroll
            for (int t = 0; t < 4; ++t)
                *(float*)(ob + r * 256 + t * 64) = y[r][t];

        c0 = n0; c1 = n1; c2 = n2; c3 = n3;
    }
}

extern "C" void kernel_launch(void* const* d_in, const int* in_sizes, int n_in,
                              void* d_out, int out_size, void* d_ws, size_t ws_size,
                              hipStream_t stream) {
    const float* x    = (const float*)d_in[0];
    const float* z    = (const float*)d_in[1];
    const float* bias = (const float*)d_in[2];
    float* out = (float*)d_out;

    mlr_prep_kernel<<<dim3(1), dim3(64), 0, stream>>>(z, bias, d_ws);
    mlr_main_kernel<<<dim3(2048), dim3(256), 0, stream>>>(x, d_ws, out);
}

// Round 6
// 123.395 us; speedup vs baseline: 2.2220x; 1.0116x over previous
//
#include <hip/hip_runtime.h>
#include <math.h>

// MidpointMLR: B=1048576, F=64, c=1.
// out = proj( sinh( 2*z_norm * asinh( (2*(x@zu)*cosh(2b) - (1+cx2)*sinh(2b)) / max(1-cx2,eps) ) ) )

#define MLR_B 1048576

typedef __bf16 bf16x8 __attribute__((ext_vector_type(8)));
typedef float  f32x4  __attribute__((ext_vector_type(4)));

// ---------------- prep: z -> z_unit bf16 fragments + per-col constants ----------------
// k-permutation shared by A and B fragments: k = 16*i + 4*hi + j,
//   where i = 2s + (e>>2)  (load-instruction index), j = e&3, hi = lane>>4.
// ws layout: bytes [0,8192): zfrag[8][512] __bf16, frag (s*4+t):
//   zf[(s*4+t)*512 + (hi*16+col)*8 + e] = bf16( z_unit[k(s,e,hi)][16t+col] )
// bytes [8192,...): f32 cst[0..63]=2cosh(2b), [64..127]=sinh(2b), [128..191]=2*z_norm
__global__ void mlr_prep_kernel(const float* __restrict__ z,
                                const float* __restrict__ bias,
                                void* __restrict__ wsv) {
    __bf16* zf  = (__bf16*)wsv;
    float*  cst = (float*)((char*)wsv + 8192);
    int o = threadIdx.x;            // one thread per output column, 64 threads
    float n2 = 0.f;
    for (int k = 0; k < 64; ++k) { float v = z[k * 64 + o]; n2 = fmaf(v, v, n2); }
    float zn  = fmaxf(sqrtf(n2), 1e-15f);
    float inv = 1.f / zn;
    int t = o >> 4, c = o & 15;
    for (int k = 0; k < 64; ++k) {
        float zu = z[k * 64 + o] * inv;
        int i  = k >> 4;            // which 64B column-chunk (load instr)
        int j  = k & 3;
        int hi = (k >> 2) & 3;
        int s  = i >> 1;
        int e  = ((i & 1) << 2) | j;
        zf[(s * 4 + t) * 512 + (hi * 16 + c) * 8 + e] = (__bf16)zu;   // RNE fptrunc
    }
    float d = 2.f * bias[o];
    cst[o]       = 2.f * coshf(d);
    cst[64 + o]  = sinhf(d);
    cst[128 + o] = 2.f * zn;
}

// y = sinh( g * asinh(t) ) via exp2/log2, stable in |t|
// NB: __builtin_amdgcn_logf IS v_log_f32 = log2 (see __clang_hip_math.h __log2f)
__device__ __forceinline__ float poin_y(float dot, float ch2, float sh, float g,
                                        float opc, float rden) {
    float t = fmaf(dot, ch2, -(opc * sh)) * rden;
    float a = fabsf(t);
    float u = a + sqrtf(fmaf(a, a, 1.f));
    float w = __builtin_amdgcn_exp2f(g * __builtin_amdgcn_logf(u));   // u^g
    float y = 0.5f * (w - __builtin_amdgcn_rcpf(w));
    return copysignf(y, t);
}

// ---------------- main: MFMA 16x16x32 bf16, 16 rows per wave-step ----------------
__global__ __launch_bounds__(256) void mlr_main_kernel(const float* __restrict__ x,
                                                       const void* __restrict__ wsv,
                                                       float* __restrict__ out) {
    const __bf16* zf  = (const __bf16*)wsv;
    const float*  cst = (const float*)((const char*)wsv + 8192);
    const int tid  = threadIdx.x;
    const int lane = tid & 63;
    const int lo   = lane & 15;     // A-row / B-col / C-col index
    const int hi   = lane >> 4;     // k-group / C-row-group
    const int wv   = blockIdx.x * 4 + (tid >> 6);

    // one-time: B fragments (z_unit), coalesced dwordx4 per (s,t)
    bf16x8 bfr[8];
#pragma unroll
    for (int i = 0; i < 8; ++i)
        bfr[i] = *(const bf16x8*)((const char*)zf + i * 1024 + lane * 16);
    // one-time: per-col epilogue constants for cols 16t+lo
    float ch[4], sh[4], g2[4];
#pragma unroll
    for (int t = 0; t < 4; ++t) {
        ch[t] = cst[16 * t + lo];
        sh[t] = cst[64 + 16 * t + lo];
        g2[t] = cst[128 + 16 * t + lo];
    }

    const size_t rowbase0 = (size_t)wv * 128;          // 8 steps x 16 rows
    // load i hits bytes [i*64 + hi*16, +16) of row lo: 16 full 64B lines/instr
    const char* xb = (const char*)x + (rowbase0 + (size_t)lo) * 256 + hi * 16;

    // preload step 0
    f32x4 c0 = *(const f32x4*)(xb + 0);
    f32x4 c1 = *(const f32x4*)(xb + 64);
    f32x4 c2 = *(const f32x4*)(xb + 128);
    f32x4 c3 = *(const f32x4*)(xb + 192);

    for (int it = 0; it < 8; ++it) {
        f32x4 n0 = c0, n1 = c1, n2 = c2, n3 = c3;
        if (it < 7) {                                   // uniform branch: prefetch next
            const char* xn = xb + (size_t)(it + 1) * 4096;
            n0 = *(const f32x4*)(xn + 0);
            n1 = *(const f32x4*)(xn + 64);
            n2 = *(const f32x4*)(xn + 128);
            n3 = *(const f32x4*)(xn + 192);
        }

        // cx2 partial from this lane's 16 f32 (row lo, its k-slices)
        float p = 0.f;
#pragma unroll
        for (int j = 0; j < 4; ++j) {
            p = fmaf(c0[j], c0[j], p); p = fmaf(c1[j], c1[j], p);
            p = fmaf(c2[j], c2[j], p); p = fmaf(c3[j], c3[j], p);
        }
        p += __shfl_xor(p, 16);
        p += __shfl_xor(p, 32);                        // full cx2 for row lo

        // A fragments: k = 16i + 4hi + j  (same perm as B)
        bf16x8 a0, a1;
#pragma unroll
        for (int j = 0; j < 4; ++j) {
            a0[j]     = (__bf16)c0[j];
            a0[4 + j] = (__bf16)c1[j];
            a1[j]     = (__bf16)c2[j];
            a1[4 + j] = (__bf16)c3[j];
        }

        f32x4 acc[4];
#pragma unroll
        for (int t = 0; t < 4; ++t) {
            acc[t] = (f32x4){0.f, 0.f, 0.f, 0.f};
            acc[t] = __builtin_amdgcn_mfma_f32_16x16x32_bf16(a0, bfr[t],     acc[t], 0, 0, 0);
            acc[t] = __builtin_amdgcn_mfma_f32_16x16x32_bf16(a1, bfr[4 + t], acc[t], 0, 0, 0);
        }

        // epilogue: C/D map col=lo, row=4*hi+reg
        float y[4][4]; float S[4];
#pragma unroll
        for (int r = 0; r < 4; ++r) {
            float cxr  = __shfl(p, hi * 4 + r);        // cx2 of row 4*hi+r
            float opc  = 1.f + cxr;
            float rden = __builtin_amdgcn_rcpf(fmaxf(1.f - cxr, 1e-15f));
            float s0 = 0.f;
#pragma unroll
            for (int t = 0; t < 4; ++t) {
                float v = poin_y(acc[t][r], ch[t], sh[t], g2[t], opc, rden);
                y[r][t] = v;
                s0 = fmaf(v, v, s0);
            }
            S[r] = s0;
        }
#pragma unroll
        for (int r = 0; r < 4; ++r) {
            float s0 = S[r];
            s0 += __shfl_xor(s0, 1);
            s0 += __shfl_xor(s0, 2);
            s0 += __shfl_xor(s0, 4);
            s0 += __shfl_xor(s0, 8);                   // sum over all 64 cols of row
            float scale = __builtin_amdgcn_rcpf(1.f + sqrtf(1.f + s0));
#pragma unroll
            for (int t = 0; t < 4; ++t) y[r][t] *= scale;
        }

        // stores: per (r,t) lanes 0..15 write 64B contiguous -> full-line writes
        char* ob = (char*)out + (rowbase0 + it * 16 + hi * 4) * 256 + lo * 4;
#pragma unroll
        for (int r = 0; r < 4; ++r)
#pragma unroll
            for (int t = 0; t < 4; ++t)
                *(float*)(ob + r * 256 + t * 64) = y[r][t];

        c0 = n0; c1 = n1; c2 = n2; c3 = n3;
    }
}

extern "C" void kernel_launch(void* const* d_in, const int* in_sizes, int n_in,
                              void* d_out, int out_size, void* d_ws, size_t ws_size,
                              hipStream_t stream) {
    const float* x    = (const float*)d_in[0];
    const float* z    = (const float*)d_in[1];
    const float* bias = (const float*)d_in[2];
    float* out = (float*)d_out;

    mlr_prep_kernel<<<dim3(1), dim3(64), 0, stream>>>(z, bias, d_ws);
    mlr_main_kernel<<<dim3(2048), dim3(256), 0, stream>>>(x, d_ws, out);
}

// Round 7
// 120.434 us; speedup vs baseline: 2.2766x; 1.0246x over previous
//
#include <hip/hip_runtime.h>
#include <math.h>

// MidpointMLR: B=1048576, F=64, c=1.
// out = proj( sinh( 2*z_norm * asinh( (2*(x@zu)*cosh(2b) - (1+cx2)*sinh(2b)) / max(1-cx2,eps) ) ) )

#define MLR_B 1048576

typedef __bf16 bf16x8 __attribute__((ext_vector_type(8)));
typedef float  f32x4  __attribute__((ext_vector_type(4)));

// ---------------- prep: z -> z_unit bf16 fragments + per-col constants ----------------
// k-permutation shared by A and B fragments: k = 16*i + 4*hi + j,
//   where i = 2s + (e>>2)  (load-instruction index), j = e&3, hi = lane>>4.
// ws layout: bytes [0,8192): zfrag[8][512] __bf16, frag (s*4+t):
//   zf[(s*4+t)*512 + (hi*16+col)*8 + e] = bf16( z_unit[k(s,e,hi)][16t+col] )
// bytes [8192,9216): f32x4 cst4[64] = {2cosh(2b), sinh(2b), 2*z_norm, 0} per col
__global__ void mlr_prep_kernel(const float* __restrict__ z,
                                const float* __restrict__ bias,
                                void* __restrict__ wsv) {
    __bf16* zf   = (__bf16*)wsv;
    f32x4*  cst4 = (f32x4*)((char*)wsv + 8192);
    int o = threadIdx.x;            // one thread per output column, 64 threads
    float n2 = 0.f;
    for (int k = 0; k < 64; ++k) { float v = z[k * 64 + o]; n2 = fmaf(v, v, n2); }
    float zn  = fmaxf(sqrtf(n2), 1e-15f);
    float inv = 1.f / zn;
    int t = o >> 4, c = o & 15;
    for (int k = 0; k < 64; ++k) {
        float zu = z[k * 64 + o] * inv;
        int i  = k >> 4;            // which 64B column-chunk (load instr)
        int j  = k & 3;
        int hi = (k >> 2) & 3;
        int s  = i >> 1;
        int e  = ((i & 1) << 2) | j;
        zf[(s * 4 + t) * 512 + (hi * 16 + c) * 8 + e] = (__bf16)zu;   // RNE fptrunc
    }
    float d = 2.f * bias[o];
    cst4[o] = (f32x4){2.f * coshf(d), sinhf(d), 2.f * zn, 0.f};
}

// y = sinh( g * asinh(t) ) via exp2/log2, stable in |t|
// NB: __builtin_amdgcn_logf IS v_log_f32 = log2 (see __clang_hip_math.h __log2f)
__device__ __forceinline__ float poin_y(float dot, float ch2, float sh, float g,
                                        float opc, float rden) {
    float t = fmaf(dot, ch2, -(opc * sh)) * rden;
    float a = fabsf(t);
    float u = a + sqrtf(fmaf(a, a, 1.f));
    float w = __builtin_amdgcn_exp2f(g * __builtin_amdgcn_logf(u));   // u^g
    float y = 0.5f * (w - __builtin_amdgcn_rcpf(w));
    return copysignf(y, t);
}

// one 16-row MFMA step: c0..c3 = this lane's x slice (row lo, k = 16i+4hi+j)
__device__ __forceinline__ void mlr_step(f32x4 c0, f32x4 c1, f32x4 c2, f32x4 c3,
                                         const bf16x8* bfr, const f32x4* cc,
                                         int lo, int hi, char* ob) {
    // cx2 for row lo (sum across hi groups)
    float p = 0.f;
#pragma unroll
    for (int j = 0; j < 4; ++j) {
        p = fmaf(c0[j], c0[j], p); p = fmaf(c1[j], c1[j], p);
        p = fmaf(c2[j], c2[j], p); p = fmaf(c3[j], c3[j], p);
    }
    p += __shfl_xor(p, 16);
    p += __shfl_xor(p, 32);

    // A fragments (same k-perm as B)
    bf16x8 a0, a1;
#pragma unroll
    for (int j = 0; j < 4; ++j) {
        a0[j]     = (__bf16)c0[j];
        a0[4 + j] = (__bf16)c1[j];
        a1[j]     = (__bf16)c2[j];
        a1[4 + j] = (__bf16)c3[j];
    }

    f32x4 acc[4];
#pragma unroll
    for (int t = 0; t < 4; ++t) {
        acc[t] = (f32x4){0.f, 0.f, 0.f, 0.f};
        acc[t] = __builtin_amdgcn_mfma_f32_16x16x32_bf16(a0, bfr[t],     acc[t], 0, 0, 0);
        acc[t] = __builtin_amdgcn_mfma_f32_16x16x32_bf16(a1, bfr[4 + t], acc[t], 0, 0, 0);
    }

    // epilogue: C/D map col=lo, row=4*hi+reg
    float y[4][4]; float S[4];
#pragma unroll
    for (int r = 0; r < 4; ++r) {
        float cxr  = __shfl(p, hi * 4 + r);            // cx2 of row 4*hi+r
        float opc  = 1.f + cxr;
        float rden = __builtin_amdgcn_rcpf(fmaxf(1.f - cxr, 1e-15f));
        float s0 = 0.f;
#pragma unroll
        for (int t = 0; t < 4; ++t) {
            float v = poin_y(acc[t][r], cc[t].x, cc[t].y, cc[t].z, opc, rden);
            y[r][t] = v;
            s0 = fmaf(v, v, s0);
        }
        S[r] = s0;
    }
#pragma unroll
    for (int r = 0; r < 4; ++r) {
        float s0 = S[r];
        s0 += __shfl_xor(s0, 1);
        s0 += __shfl_xor(s0, 2);
        s0 += __shfl_xor(s0, 4);
        s0 += __shfl_xor(s0, 8);                       // sum over all 64 cols of row
        float scale = __builtin_amdgcn_rcpf(1.f + sqrtf(1.f + s0));
#pragma unroll
        for (int t = 0; t < 4; ++t) y[r][t] *= scale;
    }

    // stores: per (r,t) lanes 0..15 write 64B contiguous -> full-line writes
#pragma unroll
    for (int r = 0; r < 4; ++r)
#pragma unroll
        for (int t = 0; t < 4; ++t)
            *(float*)(ob + r * 256 + t * 64) = y[r][t];
}

// ---------------- main: 2 steps per wave, straight-line, all loads upfront ----------------
__global__ __launch_bounds__(256) void mlr_main_kernel(const float* __restrict__ x,
                                                       const void* __restrict__ wsv,
                                                       float* __restrict__ out) {
    const __bf16* zf   = (const __bf16*)wsv;
    const f32x4*  cst4 = (const f32x4*)((const char*)wsv + 8192);
    const int tid  = threadIdx.x;
    const int lane = tid & 63;
    const int lo   = lane & 15;     // A-row / B-col / C-col index
    const int hi   = lane >> 4;     // k-group / C-row-group
    const int wv   = blockIdx.x * 4 + (tid >> 6);

    // B fragments (z_unit): 8 coalesced dwordx4 (L2-resident)
    bf16x8 bfr[8];
#pragma unroll
    for (int i = 0; i < 8; ++i)
        bfr[i] = *(const bf16x8*)((const char*)zf + i * 1024 + lane * 16);
    // per-col epilogue constants, packed: cc[t] = {2cosh, sinh, 2zn, -} for col 16t+lo
    f32x4 cc[4];
#pragma unroll
    for (int t = 0; t < 4; ++t) cc[t] = cst4[16 * t + lo];

    const size_t rowbase = (size_t)wv * 32;            // 2 steps x 16 rows
    // load i hits bytes [i*64 + hi*16, +16) of row lo: 16 full 64B lines/instr
    const char* xb = (const char*)x + (rowbase + (size_t)lo) * 256 + hi * 16;

    // issue ALL x loads for both steps upfront
    f32x4 c0 = *(const f32x4*)(xb + 0);
    f32x4 c1 = *(const f32x4*)(xb + 64);
    f32x4 c2 = *(const f32x4*)(xb + 128);
    f32x4 c3 = *(const f32x4*)(xb + 192);
    f32x4 d0 = *(const f32x4*)(xb + 4096 + 0);
    f32x4 d1 = *(const f32x4*)(xb + 4096 + 64);
    f32x4 d2 = *(const f32x4*)(xb + 4096 + 128);
    f32x4 d3 = *(const f32x4*)(xb + 4096 + 192);

    char* ob = (char*)out + (rowbase + (size_t)hi * 4) * 256 + lo * 4;
    mlr_step(c0, c1, c2, c3, bfr, cc, lo, hi, ob);
    mlr_step(d0, d1, d2, d3, bfr, cc, lo, hi, ob + 4096);
}

extern "C" void kernel_launch(void* const* d_in, const int* in_sizes, int n_in,
                              void* d_out, int out_size, void* d_ws, size_t ws_size,
                              hipStream_t stream) {
    const float* x    = (const float*)d_in[0];
    const float* z    = (const float*)d_in[1];
    const float* bias = (const float*)d_in[2];
    float* out = (float*)d_out;

    mlr_prep_kernel<<<dim3(1), dim3(64), 0, stream>>>(z, bias, d_ws);
    mlr_main_kernel<<<dim3(8192), dim3(256), 0, stream>>>(x, d_ws, out);
}

// Round 8
// 111.888 us; speedup vs baseline: 2.4505x; 1.0764x over previous
//
#include <hip/hip_runtime.h>
#include <math.h>

// MidpointMLR: B=1048576, F=64, c=1.
// out = proj( sinh( 2*z_norm * asinh( (2*(x@zu)*cosh(2b) - (1+cx2)*sinh(2b)) / max(1-cx2,eps) ) ) )

#define MLR_B 1048576

typedef __bf16 bf16x8 __attribute__((ext_vector_type(8)));
typedef float  f32x4  __attribute__((ext_vector_type(4)));

// ---------------- prep: z -> z_unit bf16 fragments + per-col constants ----------------
// k-permutation shared by A and B fragments: k = 16*i + 4*hi + j,
//   where i = 2s + (e>>2)  (load-instruction index), j = e&3, hi = lane>>4.
// Column permutation: B-fragment t, mfma-col c  <->  physical col p = 4c + t
//   (so each lane's 4 accumulators are 4 CONSECUTIVE physical cols -> dwordx4 stores).
// ws layout: bytes [0,8192): zfrag[8][512] __bf16, frag (s*4+t):
//   zf[(s*4+t)*512 + (hi*16+c)*8 + e] = bf16( z_unit[k(s,e,hi)][4c+t] )
// bytes [8192,9216): f32x4 cst4[64] = {2cosh(2b), sinh(2b), 2*z_norm, 0} per physical col
__global__ void mlr_prep_kernel(const float* __restrict__ z,
                                const float* __restrict__ bias,
                                void* __restrict__ wsv) {
    __bf16* zf   = (__bf16*)wsv;
    f32x4*  cst4 = (f32x4*)((char*)wsv + 8192);
    int o = threadIdx.x;            // one thread per physical output column, 64 threads
    float n2 = 0.f;
    for (int k = 0; k < 64; ++k) { float v = z[k * 64 + o]; n2 = fmaf(v, v, n2); }
    float zn  = fmaxf(sqrtf(n2), 1e-15f);
    float inv = 1.f / zn;
    int t = o & 3, c = o >> 2;      // fragment index, mfma-col slot
    for (int k = 0; k < 64; ++k) {
        float zu = z[k * 64 + o] * inv;
        int i  = k >> 4;            // which 64B column-chunk (load instr)
        int j  = k & 3;
        int hi = (k >> 2) & 3;
        int s  = i >> 1;
        int e  = ((i & 1) << 2) | j;
        zf[(s * 4 + t) * 512 + (hi * 16 + c) * 8 + e] = (__bf16)zu;   // RNE fptrunc
    }
    float d = 2.f * bias[o];
    cst4[o] = (f32x4){2.f * coshf(d), sinhf(d), 2.f * zn, 0.f};
}

// y = sinh( g * asinh(t) ) via exp2/log2, stable in |t|
// NB: __builtin_amdgcn_logf IS v_log_f32 = log2 (see __clang_hip_math.h __log2f)
__device__ __forceinline__ float poin_y(float dot, float ch2, float sh, float g,
                                        float opc, float rden) {
    float t = fmaf(dot, ch2, -(opc * sh)) * rden;
    float a = fabsf(t);
    float u = a + sqrtf(fmaf(a, a, 1.f));
    float w = __builtin_amdgcn_exp2f(g * __builtin_amdgcn_logf(u));   // u^g
    float y = 0.5f * (w - __builtin_amdgcn_rcpf(w));
    return copysignf(y, t);
}

// one 16-row MFMA step: c0..c3 = this lane's x slice (row lo, k = 16i+4hi+j)
__device__ __forceinline__ void mlr_step(f32x4 c0, f32x4 c1, f32x4 c2, f32x4 c3,
                                         const bf16x8* bfr, const f32x4* cc,
                                         int lo, int hi, char* ob) {
    // cx2 for row lo (sum across hi groups)
    float p = 0.f;
#pragma unroll
    for (int j = 0; j < 4; ++j) {
        p = fmaf(c0[j], c0[j], p); p = fmaf(c1[j], c1[j], p);
        p = fmaf(c2[j], c2[j], p); p = fmaf(c3[j], c3[j], p);
    }
    p += __shfl_xor(p, 16);
    p += __shfl_xor(p, 32);

    // A fragments (same k-perm as B)
    bf16x8 a0, a1;
#pragma unroll
    for (int j = 0; j < 4; ++j) {
        a0[j]     = (__bf16)c0[j];
        a0[4 + j] = (__bf16)c1[j];
        a1[j]     = (__bf16)c2[j];
        a1[4 + j] = (__bf16)c3[j];
    }

    f32x4 acc[4];
#pragma unroll
    for (int t = 0; t < 4; ++t) {
        acc[t] = (f32x4){0.f, 0.f, 0.f, 0.f};
        acc[t] = __builtin_amdgcn_mfma_f32_16x16x32_bf16(a0, bfr[t],     acc[t], 0, 0, 0);
        acc[t] = __builtin_amdgcn_mfma_f32_16x16x32_bf16(a1, bfr[4 + t], acc[t], 0, 0, 0);
    }

    // epilogue: C/D map col=lo, row=4*hi+reg; acc[t][r] = physical col 4*lo+t
    f32x4 yv[4]; float S[4];
#pragma unroll
    for (int r = 0; r < 4; ++r) {
        float cxr  = __shfl(p, hi * 4 + r);            // cx2 of row 4*hi+r
        float opc  = 1.f + cxr;
        float rden = __builtin_amdgcn_rcpf(fmaxf(1.f - cxr, 1e-15f));
        float s0 = 0.f;
        f32x4 y;
#pragma unroll
        for (int t = 0; t < 4; ++t) {
            float v = poin_y(acc[t][r], cc[t].x, cc[t].y, cc[t].z, opc, rden);
            y[t] = v;
            s0 = fmaf(v, v, s0);
        }
        yv[r] = y;
        S[r] = s0;
    }
#pragma unroll
    for (int r = 0; r < 4; ++r) {
        float s0 = S[r];
        s0 += __shfl_xor(s0, 1);
        s0 += __shfl_xor(s0, 2);
        s0 += __shfl_xor(s0, 4);
        s0 += __shfl_xor(s0, 8);                       // sum over all 64 cols of row
        float scale = __builtin_amdgcn_rcpf(1.f + sqrtf(1.f + s0));
        f32x4 y = yv[r];
        y[0] *= scale; y[1] *= scale; y[2] *= scale; y[3] *= scale;
        yv[r] = y;
    }

    // stores: one dwordx4 per r; 64 lanes cover rows {4hi+r} x cols 4lo..4lo+3
    //   = 4 x 256B fully-contiguous rows per instruction (fill-kernel-shaped)
#pragma unroll
    for (int r = 0; r < 4; ++r)
        *(f32x4*)(ob + r * 256) = yv[r];
}

// ---------------- main: 2 steps per wave, straight-line, all loads upfront ----------------
__global__ __launch_bounds__(256) void mlr_main_kernel(const float* __restrict__ x,
                                                       const void* __restrict__ wsv,
                                                       float* __restrict__ out) {
    const __bf16* zf   = (const __bf16*)wsv;
    const f32x4*  cst4 = (const f32x4*)((const char*)wsv + 8192);
    const int tid  = threadIdx.x;
    const int lane = tid & 63;
    const int lo   = lane & 15;     // A-row / B-col / C-col index
    const int hi   = lane >> 4;     // k-group / C-row-group
    const int wv   = blockIdx.x * 4 + (tid >> 6);

    // B fragments (z_unit): 8 coalesced dwordx4 (L2-resident)
    bf16x8 bfr[8];
#pragma unroll
    for (int i = 0; i < 8; ++i)
        bfr[i] = *(const bf16x8*)((const char*)zf + i * 1024 + lane * 16);
    // per-col epilogue constants for physical cols 4lo+t (64B contiguous per lane)
    f32x4 cc[4];
#pragma unroll
    for (int t = 0; t < 4; ++t) cc[t] = cst4[4 * lo + t];

    const size_t rowbase = (size_t)wv * 32;            // 2 steps x 16 rows
    // load i hits bytes [i*64 + hi*16, +16) of row lo: 16 full 64B lines/instr
    const char* xb = (const char*)x + (rowbase + (size_t)lo) * 256 + hi * 16;

    // issue ALL x loads for both steps upfront
    f32x4 c0 = *(const f32x4*)(xb + 0);
    f32x4 c1 = *(const f32x4*)(xb + 64);
    f32x4 c2 = *(const f32x4*)(xb + 128);
    f32x4 c3 = *(const f32x4*)(xb + 192);
    f32x4 d0 = *(const f32x4*)(xb + 4096 + 0);
    f32x4 d1 = *(const f32x4*)(xb + 4096 + 64);
    f32x4 d2 = *(const f32x4*)(xb + 4096 + 128);
    f32x4 d3 = *(const f32x4*)(xb + 4096 + 192);

    char* ob = (char*)out + (rowbase + (size_t)hi * 4) * 256 + lo * 16;
    mlr_step(c0, c1, c2, c3, bfr, cc, lo, hi, ob);
    mlr_step(d0, d1, d2, d3, bfr, cc, lo, hi, ob + 4096);
}

extern "C" void kernel_launch(void* const* d_in, const int* in_sizes, int n_in,
                              void* d_out, int out_size, void* d_ws, size_t ws_size,
                              hipStream_t stream) {
    const float* x    = (const float*)d_in[0];
    const float* z    = (const float*)d_in[1];
    const float* bias = (const float*)d_in[2];
    float* out = (float*)d_out;

    mlr_prep_kernel<<<dim3(1), dim3(64), 0, stream>>>(z, bias, d_ws);
    mlr_main_kernel<<<dim3(8192), dim3(256), 0, stream>>>(x, d_ws, out);
}